// Round 1
// baseline (201015.247 us; speedup 1.0000x reference)
//
#include <hip/hip_runtime.h>
#include <math.h>

#define R_DIM 4096
#define I_DIM 64
#define O_DIM 64
#define T_DIM 8192
#define NBLK  256
#define NTHR  512
#define RPB   16          // reservoir rows per block
#define NGRP  16          // barrier tree groups (16 blocks each)
#define CTR_STRIDE 32     // ints -> 128B between counters

// d_ws layout:
//   [0 .. 32KB)  : S double buffer (2 x 4096 floats)
//   [32KB .. )   : ctr[NGRP * CTR_STRIDE] ints

__global__ __launch_bounds__(NTHR, 2) void esn_persist(
    const float* __restrict__ X, const float* __restrict__ Wres,
    const float* __restrict__ Win, const float* __restrict__ Wout,
    float* __restrict__ out, float* __restrict__ S, int* __restrict__ ctr)
{
    __shared__ __align__(16) float lds_s[2][R_DIM + I_DIM];
    __shared__ float4 red4[8];
    __shared__ float  snew[RPB];

    const int tid  = threadIdx.x;
    const int b    = blockIdx.x;
    const int lane = tid & 63;
    const int w    = tid >> 6;        // wave 0..7
    const int rg   = tid >> 7;        // 0..3 : row group (4 rows each)
    const int cg   = tid & 127;       // 0..127: column group
    const int R0   = b * RPB;
    const int grp  = b >> 4;

    // ---- one-time: load this block's weight slice into registers ----
    float4 wr[4][8];
#pragma unroll
    for (int rr = 0; rr < 4; ++rr) {
        const float* rowp = Wres + (size_t)(R0 + rg * 4 + rr) * R_DIM + cg * 4;
#pragma unroll
        for (int i = 0; i < 8; ++i)
            wr[rr][i] = *(const float4*)(rowp + i * 512);
    }
    float4 wi[4] = {};
    if (cg < 16) {
#pragma unroll
        for (int rr = 0; rr < 4; ++rr)
            wi[rr] = *(const float4*)(Win + (size_t)(R0 + rg * 4 + rr) * I_DIM + cg * 4);
    }
    float4 wo4[4] = {};
    if (tid < O_DIM) {
#pragma unroll
        for (int j = 0; j < 4; ++j)
            wo4[j] = *(const float4*)(Wout + (size_t)tid * (I_DIM + R_DIM) + I_DIM + R0 + j * 4);
    }

    for (int t = 0; t < T_DIM; ++t) {
        const int cur = t & 1;
        float* lds = &lds_s[cur][0];
        const float* Sread = S + ((t + 1) & 1) * R_DIM;   // == S[(t-1)&1]; S[1] pre-zeroed for t=0

        // ---- stage prev state (16KB) + x_t (256B) into LDS, coalesced ----
        {
            const float4* src = (const float4*)Sread;
            float4 a0 = src[tid];
            float4 a1 = src[tid + NTHR];
            ((float4*)lds)[tid]        = a0;
            ((float4*)lds)[tid + NTHR] = a1;
            if (tid < I_DIM) lds[R_DIM + tid] = X[(size_t)t * I_DIM + tid];
        }
        __syncthreads();

        // ---- partial dot products: 4 rows x 32 cols per thread ----
        float acc0 = 0.f, acc1 = 0.f, acc2 = 0.f, acc3 = 0.f;
#pragma unroll
        for (int i = 0; i < 8; ++i) {
            float4 sv = *(const float4*)&lds[cg * 4 + i * 512];
            acc0 += wr[0][i].x * sv.x + wr[0][i].y * sv.y + wr[0][i].z * sv.z + wr[0][i].w * sv.w;
            acc1 += wr[1][i].x * sv.x + wr[1][i].y * sv.y + wr[1][i].z * sv.z + wr[1][i].w * sv.w;
            acc2 += wr[2][i].x * sv.x + wr[2][i].y * sv.y + wr[2][i].z * sv.z + wr[2][i].w * sv.w;
            acc3 += wr[3][i].x * sv.x + wr[3][i].y * sv.y + wr[3][i].z * sv.z + wr[3][i].w * sv.w;
        }
        if (cg < 16) {  // W_in contribution (x_t lives at lds[R_DIM..])
            float4 xv = *(const float4*)&lds[R_DIM + cg * 4];
            acc0 += wi[0].x * xv.x + wi[0].y * xv.y + wi[0].z * xv.z + wi[0].w * xv.w;
            acc1 += wi[1].x * xv.x + wi[1].y * xv.y + wi[1].z * xv.z + wi[1].w * xv.w;
            acc2 += wi[2].x * xv.x + wi[2].y * xv.y + wi[2].z * xv.z + wi[2].w * xv.w;
            acc3 += wi[3].x * xv.x + wi[3].y * xv.y + wi[3].z * xv.z + wi[3].w * xv.w;
        }

        // ---- wave butterfly reduce (64 lanes) ----
#pragma unroll
        for (int d = 1; d < 64; d <<= 1) {
            acc0 += __shfl_xor(acc0, d);
            acc1 += __shfl_xor(acc1, d);
            acc2 += __shfl_xor(acc2, d);
            acc3 += __shfl_xor(acc3, d);
        }
        if (lane == 0) red4[w] = make_float4(acc0, acc1, acc2, acc3);
        __syncthreads();

        // ---- tail: finish rows, tanh, publish slice, readout, arrive ----
        if (w == 0) {
            if (lane < RPB) {
                const int rgp = lane >> 2, rr = lane & 3;
                float pre = ((const float*)&red4[rgp * 2])[rr] + ((const float*)&red4[rgp * 2 + 1])[rr];
                float s = tanhf(pre);
                S[cur * R_DIM + R0 + lane] = s;   // plain store, fenced below
                snew[lane] = s;
            }
            __builtin_amdgcn_fence(__ATOMIC_RELEASE, "agent");  // flush slice to coherent point
            if (lane == 0 && t != T_DIM - 1)
                __hip_atomic_fetch_add(&ctr[grp * CTR_STRIDE], 1, __ATOMIC_RELAXED, __HIP_MEMORY_SCOPE_AGENT);

            // readout (state part): y[o] += Wout[o, 64+R0 .. +16] . snew
            float y = 0.f;
#pragma unroll
            for (int j = 0; j < 4; ++j) {
                y += wo4[j].x * snew[j * 4 + 0] + wo4[j].y * snew[j * 4 + 1]
                   + wo4[j].z * snew[j * 4 + 2] + wo4[j].w * snew[j * 4 + 3];
            }
            __hip_atomic_fetch_add(&out[(size_t)t * O_DIM + lane], y,
                                   __ATOMIC_RELAXED, __HIP_MEMORY_SCOPE_AGENT);
        }

        // ---- device-wide barrier: wait all 16 group counters reach 16*(t+1) ----
        if (t != T_DIM - 1) {
            const int target = NGRP * (t + 1);
            int* myctr = &ctr[(lane & (NGRP - 1)) * CTR_STRIDE];
            while (true) {
                int v = __hip_atomic_load(myctr, __ATOMIC_RELAXED, __HIP_MEMORY_SCOPE_AGENT);
                if (__all(v >= target)) break;
                __builtin_amdgcn_s_sleep(1);
            }
            __builtin_amdgcn_fence(__ATOMIC_ACQUIRE, "agent");  // invalidate stale L1/L2
        }
    }
}

// y_x[t,o] = Wout[o, :64] . x_t  -- runs BEFORE persistent kernel, plain writes
__global__ void esn_xpart(const float* __restrict__ X, const float* __restrict__ Wout,
                          float* __restrict__ out)
{
    const int idx = blockIdx.x * blockDim.x + threadIdx.x;  // t*64 + o
    const int t = idx >> 6, o = idx & 63;
    const float4* xr = (const float4*)(X + (size_t)t * I_DIM);
    const float4* wr = (const float4*)(Wout + (size_t)o * (I_DIM + R_DIM));
    float y = 0.f;
#pragma unroll
    for (int j = 0; j < 16; ++j) {
        float4 a = xr[j], b = wr[j];
        y += a.x * b.x + a.y * b.y + a.z * b.z + a.w * b.w;
    }
    out[idx] = y;
}

extern "C" void kernel_launch(void* const* d_in, const int* in_sizes, int n_in,
                              void* d_out, int out_size, void* d_ws, size_t ws_size,
                              hipStream_t stream)
{
    (void)in_sizes; (void)n_in; (void)out_size; (void)ws_size;
    const float* X    = (const float*)d_in[0];
    const float* Win  = (const float*)d_in[1];
    const float* Wres = (const float*)d_in[2];
    const float* Wout = (const float*)d_in[3];
    float* out = (float*)d_out;
    float* S   = (float*)d_ws;
    int*   ctr = (int*)((char*)d_ws + 2 * R_DIM * sizeof(float));

    // zero state double-buffer + barrier counters (required every call)
    hipMemsetAsync(d_ws, 0, 2 * R_DIM * sizeof(float) + NGRP * CTR_STRIDE * sizeof(int), stream);

    // x-part of readout writes all of d_out first
    esn_xpart<<<(T_DIM * O_DIM) / 256, 256, 0, stream>>>(X, Wout, out);

    // persistent cooperative recurrence kernel atomically adds state part
    void* args[] = { (void*)&X, (void*)&Wres, (void*)&Win, (void*)&Wout,
                     (void*)&out, (void*)&S, (void*)&ctr };
    hipLaunchCooperativeKernel((const void*)esn_persist, dim3(NBLK), dim3(NTHR),
                               args, 0, stream);
}

// Round 2
// 59088.391 us; speedup vs baseline: 3.4019x; 3.4019x over previous
//
#include <hip/hip_runtime.h>
#include <math.h>

#define R_DIM 4096
#define I_DIM 64
#define O_DIM 64
#define T_DIM 8192
#define NBLK  256
#define NTHR  512
#define RPB   16          // reservoir rows per block
#define NGRP  16          // barrier groups
#define BPG   16          // blocks per group (NBLK/NGRP)
#define CTR_STRIDE 32     // ints -> 128B between counters

// d_ws layout:
//   [0 .. 32KB)  : S double buffer (2 x 4096 floats)
//   [32KB .. )   : ctr[NGRP * CTR_STRIDE] ints

__global__ __launch_bounds__(NTHR, 2) void esn_persist(
    const float* __restrict__ X, const float* __restrict__ Wres,
    const float* __restrict__ Win, const float* __restrict__ Wout,
    float* __restrict__ out, float* __restrict__ S, int* __restrict__ ctr)
{
    __shared__ __align__(16) float lds_s[2][R_DIM + I_DIM];
    __shared__ float4 red4[8];
    __shared__ float  snew[RPB];

    const int tid  = threadIdx.x;
    const int b    = blockIdx.x;
    const int lane = tid & 63;
    const int w    = tid >> 6;        // wave 0..7
    const int rg   = tid >> 7;        // 0..3 : row group (4 rows each)
    const int cg   = tid & 127;       // 0..127: column group
    const int R0   = b * RPB;
    const int grp  = b >> 4;

    // ---- one-time: load this block's weight slice into registers ----
    float4 wr[4][8];
#pragma unroll
    for (int rr = 0; rr < 4; ++rr) {
        const float* rowp = Wres + (size_t)(R0 + rg * 4 + rr) * R_DIM + cg * 4;
#pragma unroll
        for (int i = 0; i < 8; ++i)
            wr[rr][i] = *(const float4*)(rowp + i * 512);
    }
    float4 wi[4] = {};
    if (cg < 16) {
#pragma unroll
        for (int rr = 0; rr < 4; ++rr)
            wi[rr] = *(const float4*)(Win + (size_t)(R0 + rg * 4 + rr) * I_DIM + cg * 4);
    }
    float4 wo4[4] = {};
    if (tid < O_DIM) {
#pragma unroll
        for (int j = 0; j < 4; ++j)
            wo4[j] = *(const float4*)(Wout + (size_t)tid * (I_DIM + R_DIM) + I_DIM + R0 + j * 4);
    }

    for (int t = 0; t < T_DIM; ++t) {
        const int cur = t & 1;
        float* lds = &lds_s[cur][0];
        // prev state buffer: S[(t-1)&1] == S[(t+1)&1]; S[1] pre-zeroed for t=0
        const unsigned long long* src =
            (const unsigned long long*)(S + ((t + 1) & 1) * R_DIM);

        // ---- stage prev state via per-access coherent 8B loads (bypass stale L2) ----
        {
            unsigned long long v0 = __hip_atomic_load(&src[tid           ], __ATOMIC_RELAXED, __HIP_MEMORY_SCOPE_AGENT);
            unsigned long long v1 = __hip_atomic_load(&src[tid + 1 * NTHR], __ATOMIC_RELAXED, __HIP_MEMORY_SCOPE_AGENT);
            unsigned long long v2 = __hip_atomic_load(&src[tid + 2 * NTHR], __ATOMIC_RELAXED, __HIP_MEMORY_SCOPE_AGENT);
            unsigned long long v3 = __hip_atomic_load(&src[tid + 3 * NTHR], __ATOMIC_RELAXED, __HIP_MEMORY_SCOPE_AGENT);
            unsigned long long* dst = (unsigned long long*)lds;
            dst[tid           ] = v0;
            dst[tid + 1 * NTHR] = v1;
            dst[tid + 2 * NTHR] = v2;
            dst[tid + 3 * NTHR] = v3;
            if (tid < I_DIM) lds[R_DIM + tid] = X[(size_t)t * I_DIM + tid];
        }
        __syncthreads();

        // ---- partial dot products: 4 rows x 32 cols per thread ----
        float acc0 = 0.f, acc1 = 0.f, acc2 = 0.f, acc3 = 0.f;
#pragma unroll
        for (int i = 0; i < 8; ++i) {
            float4 sv = *(const float4*)&lds[cg * 4 + i * 512];
            acc0 += wr[0][i].x * sv.x + wr[0][i].y * sv.y + wr[0][i].z * sv.z + wr[0][i].w * sv.w;
            acc1 += wr[1][i].x * sv.x + wr[1][i].y * sv.y + wr[1][i].z * sv.z + wr[1][i].w * sv.w;
            acc2 += wr[2][i].x * sv.x + wr[2][i].y * sv.y + wr[2][i].z * sv.z + wr[2][i].w * sv.w;
            acc3 += wr[3][i].x * sv.x + wr[3][i].y * sv.y + wr[3][i].z * sv.z + wr[3][i].w * sv.w;
        }
        if (cg < 16) {  // W_in contribution (x_t lives at lds[R_DIM..])
            float4 xv = *(const float4*)&lds[R_DIM + cg * 4];
            acc0 += wi[0].x * xv.x + wi[0].y * xv.y + wi[0].z * xv.z + wi[0].w * xv.w;
            acc1 += wi[1].x * xv.x + wi[1].y * xv.y + wi[1].z * xv.z + wi[1].w * xv.w;
            acc2 += wi[2].x * xv.x + wi[2].y * xv.y + wi[2].z * xv.z + wi[2].w * xv.w;
            acc3 += wi[3].x * xv.x + wi[3].y * xv.y + wi[3].z * xv.z + wi[3].w * xv.w;
        }

        // ---- wave butterfly reduce (64 lanes) ----
#pragma unroll
        for (int d = 1; d < 64; d <<= 1) {
            acc0 += __shfl_xor(acc0, d);
            acc1 += __shfl_xor(acc1, d);
            acc2 += __shfl_xor(acc2, d);
            acc3 += __shfl_xor(acc3, d);
        }
        if (lane == 0) red4[w] = make_float4(acc0, acc1, acc2, acc3);
        __syncthreads();

        // ---- wave0 tail: finish rows, tanh, publish (coherent stores), arrive, readout ----
        if (w == 0) {
            if (lane < RPB) {
                const int rgp = lane >> 2, rr = lane & 3;
                float pre = ((const float*)&red4[rgp * 2])[rr] + ((const float*)&red4[rgp * 2 + 1])[rr];
                float s = tanhf(pre);
                // per-access coherent store: lands at the device coherent point, no L2 sweep
                __hip_atomic_store(&S[cur * R_DIM + R0 + lane], s,
                                   __ATOMIC_RELAXED, __HIP_MEMORY_SCOPE_AGENT);
                snew[lane] = s;
            }
            // ensure state stores reached the coherent point before signaling arrival
            asm volatile("s_waitcnt vmcnt(0)" ::: "memory");
            if (lane == 0 && t != T_DIM - 1)
                __hip_atomic_fetch_add(&ctr[grp * CTR_STRIDE], 1,
                                       __ATOMIC_RELAXED, __HIP_MEMORY_SCOPE_AGENT);

            // readout (state part): y[o] += Wout[o, 64+R0 .. +16] . snew
            float y = 0.f;
#pragma unroll
            for (int j = 0; j < 4; ++j) {
                y += wo4[j].x * snew[j * 4 + 0] + wo4[j].y * snew[j * 4 + 1]
                   + wo4[j].z * snew[j * 4 + 2] + wo4[j].w * snew[j * 4 + 3];
            }
            __hip_atomic_fetch_add(&out[(size_t)t * O_DIM + lane], y,
                                   __ATOMIC_RELAXED, __HIP_MEMORY_SCOPE_AGENT);
        }

        // ---- device-wide barrier: wave7 polls, everyone else idles in syncthreads ----
        if (t != T_DIM - 1) {
            if (w == 7) {
                const int target = BPG * (t + 1);
                int* myctr = &ctr[(lane & (NGRP - 1)) * CTR_STRIDE];
                while (true) {
                    int v = __hip_atomic_load(myctr, __ATOMIC_RELAXED, __HIP_MEMORY_SCOPE_AGENT);
                    if (__all(v >= target)) break;
                    __builtin_amdgcn_s_sleep(1);
                }
            }
            __syncthreads();
        }
    }
}

// y_x[t,o] = Wout[o, :64] . x_t  -- runs BEFORE persistent kernel, plain writes
__global__ void esn_xpart(const float* __restrict__ X, const float* __restrict__ Wout,
                          float* __restrict__ out)
{
    const int idx = blockIdx.x * blockDim.x + threadIdx.x;  // t*64 + o
    const int t = idx >> 6, o = idx & 63;
    const float4* xr = (const float4*)(X + (size_t)t * I_DIM);
    const float4* wr = (const float4*)(Wout + (size_t)o * (I_DIM + R_DIM));
    float y = 0.f;
#pragma unroll
    for (int j = 0; j < 16; ++j) {
        float4 a = xr[j], b = wr[j];
        y += a.x * b.x + a.y * b.y + a.z * b.z + a.w * b.w;
    }
    out[idx] = y;
}

extern "C" void kernel_launch(void* const* d_in, const int* in_sizes, int n_in,
                              void* d_out, int out_size, void* d_ws, size_t ws_size,
                              hipStream_t stream)
{
    (void)in_sizes; (void)n_in; (void)out_size; (void)ws_size;
    const float* X    = (const float*)d_in[0];
    const float* Win  = (const float*)d_in[1];
    const float* Wres = (const float*)d_in[2];
    const float* Wout = (const float*)d_in[3];
    float* out = (float*)d_out;
    float* S   = (float*)d_ws;
    int*   ctr = (int*)((char*)d_ws + 2 * R_DIM * sizeof(float));

    // zero state double-buffer + barrier counters (required every call)
    hipMemsetAsync(d_ws, 0, 2 * R_DIM * sizeof(float) + NGRP * CTR_STRIDE * sizeof(int), stream);

    // x-part of readout writes all of d_out first
    esn_xpart<<<(T_DIM * O_DIM) / 256, 256, 0, stream>>>(X, Wout, out);

    // persistent cooperative recurrence kernel atomically adds state part
    void* args[] = { (void*)&X, (void*)&Wres, (void*)&Win, (void*)&Wout,
                     (void*)&out, (void*)&S, (void*)&ctr };
    hipLaunchCooperativeKernel((const void*)esn_persist, dim3(NBLK), dim3(NTHR),
                               args, 0, stream);
}